// Round 3
// baseline (1734.262 us; speedup 1.0000x reference)
//
#include <hip/hip_runtime.h>
#include <cstdint>
#include <cstddef>

// Problem constants (Swin window attention)
#define B_WIN   2048
#define N_TOK   64
#define C_DIM   512
#define H_HEADS 16
#define D_HEAD  32
#define K_DIM   512
#define M_ROWS  (B_WIN * N_TOK)   // 131072

typedef __bf16 bf16x8 __attribute__((ext_vector_type(8)));
typedef float  f32x4  __attribute__((ext_vector_type(4)));
typedef unsigned short u16x8 __attribute__((ext_vector_type(8)));

__device__ __forceinline__ unsigned short f2bf_rn(float f) {
    unsigned u = __float_as_uint(f);
    u += 0x7fffu + ((u >> 16) & 1u);
    return (unsigned short)(u >> 16);
}
__device__ __forceinline__ float bf2f(unsigned short h) {
    return __uint_as_float(((unsigned)h) << 16);
}
__device__ __forceinline__ void gload16(const void* g, void* l) {
    __builtin_amdgcn_global_load_lds(
        (const __attribute__((address_space(1))) void*)g,
        (__attribute__((address_space(3))) void*)l,
        16, 0, 0);
}

// ---------------------------------------------------------------------------
// xsplit: A [M][512] fp32 -> Ah/Al [M][512] bf16 (hi/lo residual split)
// ---------------------------------------------------------------------------
__global__ __launch_bounds__(256) void xsplit_kernel(
    const float* __restrict__ x,
    unsigned short* __restrict__ Xh,
    unsigned short* __restrict__ Xl)
{
    size_t i = ((size_t)blockIdx.x * 256 + threadIdx.x) * 8;
    float4 f0 = *reinterpret_cast<const float4*>(&x[i]);
    float4 f1 = *reinterpret_cast<const float4*>(&x[i + 4]);
    float fv[8] = {f0.x, f0.y, f0.z, f0.w, f1.x, f1.y, f1.z, f1.w};
    u16x8 hi, lo;
#pragma unroll
    for (int j = 0; j < 8; ++j) {
        unsigned short h = f2bf_rn(fv[j]);
        hi[j] = h;
        lo[j] = f2bf_rn(fv[j] - bf2f(h));
    }
    *reinterpret_cast<u16x8*>(&Xh[i]) = hi;
    *reinterpret_cast<u16x8*>(&Xl[i]) = lo;
}

// ---------------------------------------------------------------------------
// Weight transpose + bf16 hi/lo split: w[K=512][N] -> wTh/wTl[N][512]
// ---------------------------------------------------------------------------
__global__ __launch_bounds__(256) void wsplit_kernel(
    const float* __restrict__ w,
    unsigned short* __restrict__ wTh,
    unsigned short* __restrict__ wTl,
    int Ncols)
{
    int idx = blockIdx.x * 256 + threadIdx.x;   // idx = n*512 + k
    int n = idx >> 9;
    int k = idx & 511;
    float v = w[(size_t)k * Ncols + n];
    unsigned short hi = f2bf_rn(v);
    wTh[idx] = hi;
    wTl[idx] = f2bf_rn(v - bf2f(hi));
}

// ---------------------------------------------------------------------------
// bf16x3-split MFMA GEMM, all operands pre-split bf16 [.][512], staged purely
// via global_load_lds. 128x128 tile, BK=32, 4 waves, mfma_f32_16x16x32_bf16.
//   mode 0: scatter into qkv[3][B][H][N][D]
//   mode 1: add bias, store row-major [M][Ncols_out]
// ---------------------------------------------------------------------------
__global__ __launch_bounds__(256) void gemm_mfma_kernel(
    const unsigned short* __restrict__ ATh,  // [M][512]
    const unsigned short* __restrict__ ATl,
    const unsigned short* __restrict__ BTh,  // [N][512]
    const unsigned short* __restrict__ BTl,
    int mode,
    float* __restrict__ qkv_out,
    const float* __restrict__ bias,
    float* __restrict__ out,
    int Ncols_out)
{
    __shared__ __align__(16) unsigned short Ah[4096];  // [128 m][32 k]
    __shared__ __align__(16) unsigned short Al[4096];
    __shared__ __align__(16) unsigned short Bh[4096];  // [128 n][32 k]
    __shared__ __align__(16) unsigned short Bl[4096];

    const int t    = threadIdx.x;
    const int lane = t & 63;
    const int wave = t >> 6;
    const int lg   = lane >> 4;      // 0..3  (k-group)
    const int lr   = lane & 15;      // 0..15 (m / n within fragment)
    const int m0   = blockIdx.y * 128;
    const int n0   = blockIdx.x * 128;
    const int wrow = (wave >> 1) * 64;
    const int wcol = (wave & 1) * 64;

    f32x4 acc[4][4];
#pragma unroll
    for (int i = 0; i < 4; ++i)
#pragma unroll
        for (int j = 0; j < 4; ++j) acc[i][j] = (f32x4){0.f, 0.f, 0.f, 0.f};

    for (int k0 = 0; k0 < K_DIM; k0 += 32) {
        __syncthreads();   // previous tile fully consumed
        // stage 4 operands: 2 chunks/thread each, 16B wide, linear LDS
#pragma unroll
        for (int i = 0; i < 2; ++i) {
            const int c    = i * 256 + t;        // 16B chunk id, wave-contiguous
            const int row  = c >> 2;             // 0..127
            const int slot = (c & 3) * 8;        // bf16 elems within 64B row
            const size_t ga = (size_t)(m0 + row) * 512 + k0 + slot;
            const size_t gb = (size_t)(n0 + row) * 512 + k0 + slot;
            gload16(&ATh[ga], &Ah[c * 8]);
            gload16(&ATl[ga], &Al[c * 8]);
            gload16(&BTh[gb], &Bh[c * 8]);
            gload16(&BTl[gb], &Bl[c * 8]);
        }
        __syncthreads();   // drains vmcnt: DMA complete

        bf16x8 ah[4], al[4];
#pragma unroll
        for (int mi = 0; mi < 4; ++mi) {
            const int off = (wrow + mi * 16 + lr) * 32 + lg * 8;
            ah[mi] = *reinterpret_cast<const bf16x8*>(&Ah[off]);
            al[mi] = *reinterpret_cast<const bf16x8*>(&Al[off]);
        }
#pragma unroll
        for (int ni = 0; ni < 4; ++ni) {
            const int off = (wcol + ni * 16 + lr) * 32 + lg * 8;
            bf16x8 bh = *reinterpret_cast<const bf16x8*>(&Bh[off]);
            bf16x8 bl = *reinterpret_cast<const bf16x8*>(&Bl[off]);
#pragma unroll
            for (int mi = 0; mi < 4; ++mi) {
                acc[mi][ni] = __builtin_amdgcn_mfma_f32_16x16x32_bf16(ah[mi], bh, acc[mi][ni], 0, 0, 0);
                acc[mi][ni] = __builtin_amdgcn_mfma_f32_16x16x32_bf16(ah[mi], bl, acc[mi][ni], 0, 0, 0);
                acc[mi][ni] = __builtin_amdgcn_mfma_f32_16x16x32_bf16(al[mi], bh, acc[mi][ni], 0, 0, 0);
            }
        }
    }

    // C/D layout: col = lane&15, row = (lane>>4)*4 + reg   [m89-verified]
    if (mode == 0) {
#pragma unroll
        for (int mi = 0; mi < 4; ++mi)
#pragma unroll
            for (int ni = 0; ni < 4; ++ni) {
                const int col  = n0 + wcol + ni * 16 + lr;
                const int tsel = col >> 9;
                const int h    = (col >> 5) & 15;
                const int dd   = col & 31;
#pragma unroll
                for (int reg = 0; reg < 4; ++reg) {
                    const int row = m0 + wrow + mi * 16 + lg * 4 + reg;
                    const int b = row >> 6, n = row & 63;
                    qkv_out[((((size_t)tsel * B_WIN + b) * H_HEADS + h) * N_TOK + n) * D_HEAD + dd]
                        = acc[mi][ni][reg];
                }
            }
    } else {
#pragma unroll
        for (int mi = 0; mi < 4; ++mi)
#pragma unroll
            for (int ni = 0; ni < 4; ++ni) {
                const int col = n0 + wcol + ni * 16 + lr;
                const float pb = bias[col];
#pragma unroll
                for (int reg = 0; reg < 4; ++reg) {
                    const int row = m0 + wrow + mi * 16 + lg * 4 + reg;
                    out[(size_t)row * Ncols_out + col] = acc[mi][ni][reg] + pb;
                }
            }
    }
}

// ---------------------------------------------------------------------------
// Kernel 2: per-(b,h) window attention; emits av pre-split as avh/avl bf16
// ---------------------------------------------------------------------------
__global__ __launch_bounds__(256) void attn_kernel(
    const float* __restrict__ qkv,        // [3][B][H][N][D]
    const float* __restrict__ bias_table, // [(2ws-1)^2][H]
    const int*   __restrict__ rel_index,  // [64][64]
    float* __restrict__ attn_map,         // [B][H][64][64]
    unsigned short* __restrict__ avh,     // [B][N][H][D] = [M][512] bf16 hi
    unsigned short* __restrict__ avl)     // lo
{
    __shared__ float qs[64][36];
    __shared__ float ks[64][36];
    __shared__ float vs[64][36];
    __shared__ float ps[64][65];

    const int bh = blockIdx.x;
    const int b  = bh >> 4;
    const int h  = bh & 15;
    const int t  = threadIdx.x;

    const size_t plane = (size_t)B_WIN * H_HEADS * N_TOK * D_HEAD;
    const size_t base  = (size_t)bh * (N_TOK * D_HEAD);
    const float* qg = qkv + base;
    const float* kg = qkv + plane + base;
    const float* vg = qkv + 2 * plane + base;

    const int lr = t >> 2;
    const int lc = (t & 3) * 8;
    {
        float4 x0 = *reinterpret_cast<const float4*>(&qg[lr * 32 + lc]);
        float4 x1 = *reinterpret_cast<const float4*>(&qg[lr * 32 + lc + 4]);
        *reinterpret_cast<float4*>(&qs[lr][lc])     = x0;
        *reinterpret_cast<float4*>(&qs[lr][lc + 4]) = x1;
        float4 y0 = *reinterpret_cast<const float4*>(&kg[lr * 32 + lc]);
        float4 y1 = *reinterpret_cast<const float4*>(&kg[lr * 32 + lc + 4]);
        *reinterpret_cast<float4*>(&ks[lr][lc])     = y0;
        *reinterpret_cast<float4*>(&ks[lr][lc + 4]) = y1;
        float4 z0 = *reinterpret_cast<const float4*>(&vg[lr * 32 + lc]);
        float4 z1 = *reinterpret_cast<const float4*>(&vg[lr * 32 + lc + 4]);
        *reinterpret_cast<float4*>(&vs[lr][lc])     = z0;
        *reinterpret_cast<float4*>(&vs[lr][lc + 4]) = z1;
    }
    __syncthreads();

    const int r  = t >> 2;
    const int c0 = (t & 3) * 16;

    float qr[32];
#pragma unroll
    for (int u = 0; u < 8; ++u) {
        float4 qf = *reinterpret_cast<const float4*>(&qs[r][u * 4]);
        qr[u * 4 + 0] = qf.x; qr[u * 4 + 1] = qf.y;
        qr[u * 4 + 2] = qf.z; qr[u * 4 + 3] = qf.w;
    }

    const float scale = 0.1767766952966369f;  // 32^-0.5
    float p[16];
#pragma unroll
    for (int j = 0; j < 16; ++j) {
        const int c = c0 + j;
        float s = 0.f;
#pragma unroll
        for (int kk = 0; kk < 32; kk += 4) {
            float4 kf = *reinterpret_cast<const float4*>(&ks[c][kk]);
            s = fmaf(qr[kk + 0], kf.x, s);
            s = fmaf(qr[kk + 1], kf.y, s);
            s = fmaf(qr[kk + 2], kf.z, s);
            s = fmaf(qr[kk + 3], kf.w, s);
        }
        p[j] = fmaf(s, scale, bias_table[rel_index[(r << 6) + c] * H_HEADS + h]);
    }

    float mx = p[0];
#pragma unroll
    for (int j = 1; j < 16; ++j) mx = fmaxf(mx, p[j]);
    mx = fmaxf(mx, __shfl_xor(mx, 1));
    mx = fmaxf(mx, __shfl_xor(mx, 2));
    float sum = 0.f;
#pragma unroll
    for (int j = 0; j < 16; ++j) { p[j] = __expf(p[j] - mx); sum += p[j]; }
    sum += __shfl_xor(sum, 1);
    sum += __shfl_xor(sum, 2);
    const float inv = 1.0f / sum;
#pragma unroll
    for (int j = 0; j < 16; ++j) p[j] *= inv;

#pragma unroll
    for (int j = 0; j < 16; ++j) ps[r][c0 + j] = p[j];

    {
        size_t ab = ((size_t)bh * 64 + r) * 64 + c0;
        *reinterpret_cast<float4*>(&attn_map[ab + 0])  = make_float4(p[0],  p[1],  p[2],  p[3]);
        *reinterpret_cast<float4*>(&attn_map[ab + 4])  = make_float4(p[4],  p[5],  p[6],  p[7]);
        *reinterpret_cast<float4*>(&attn_map[ab + 8])  = make_float4(p[8],  p[9],  p[10], p[11]);
        *reinterpret_cast<float4*>(&attn_map[ab + 12]) = make_float4(p[12], p[13], p[14], p[15]);
    }
    __syncthreads();

    const int dd0 = (t & 3) * 8;
    float acc[8];
#pragma unroll
    for (int u = 0; u < 8; ++u) acc[u] = 0.f;
#pragma unroll 8
    for (int j = 0; j < 64; ++j) {
        const float pv = ps[r][j];
        float4 v0 = *reinterpret_cast<const float4*>(&vs[j][dd0]);
        float4 v1 = *reinterpret_cast<const float4*>(&vs[j][dd0 + 4]);
        acc[0] = fmaf(pv, v0.x, acc[0]);
        acc[1] = fmaf(pv, v0.y, acc[1]);
        acc[2] = fmaf(pv, v0.z, acc[2]);
        acc[3] = fmaf(pv, v0.w, acc[3]);
        acc[4] = fmaf(pv, v1.x, acc[4]);
        acc[5] = fmaf(pv, v1.y, acc[5]);
        acc[6] = fmaf(pv, v1.z, acc[6]);
        acc[7] = fmaf(pv, v1.w, acc[7]);
    }
    // emit pre-split hi/lo bf16 (feeds proj GEMM's MFMA path directly)
    u16x8 hv, lv;
#pragma unroll
    for (int u = 0; u < 8; ++u) {
        unsigned short hh = f2bf_rn(acc[u]);
        hv[u] = hh;
        lv[u] = f2bf_rn(acc[u] - bf2f(hh));
    }
    size_t o = (((size_t)b * 64 + r) * 16 + h) * 32 + dd0;
    *reinterpret_cast<u16x8*>(&avh[o]) = hv;
    *reinterpret_cast<u16x8*>(&avl[o]) = lv;
}

// ---------------------------------------------------------------------------
extern "C" void kernel_launch(void* const* d_in, const int* in_sizes, int n_in,
                              void* d_out, int out_size, void* d_ws, size_t ws_size,
                              hipStream_t stream) {
    const float* x          = (const float*)d_in[0];
    const float* qkv_w      = (const float*)d_in[1];
    const float* proj_w     = (const float*)d_in[2];
    const float* proj_b     = (const float*)d_in[3];
    const float* bias_table = (const float*)d_in[4];
    const int*   rel_index  = (const int*)d_in[5];

    float* out      = (float*)d_out;                           // [131072][512]
    float* attn_map = (float*)d_out + (size_t)M_ROWS * C_DIM;  // [B][H][64][64]

    // d_ws layout (exactly 1 GiB):
    //   Xh [M][512] bf16 | Xl [M][512] bf16 | qkv [3][B][H][N][D] fp32
    // avh/avl alias Xh/Xl (dead after QKV GEMM; attn writes them after).
    unsigned short* Xh  = (unsigned short*)d_ws;
    unsigned short* Xl  = Xh + (size_t)M_ROWS * 512;
    float*          qkv = (float*)(Xl + (size_t)M_ROWS * 512);
    unsigned short* avh = Xh;
    unsigned short* avl = Xl;

    // qkv_w split parks in the attn_map region of d_out (dead until attn,
    // which fully overwrites it). proj_w split parks at qkv head (dead after
    // attn reads qkv; wsplit launches after attn in stream order).
    unsigned short* qwTh = (unsigned short*)attn_map;
    unsigned short* qwTl = qwTh + (size_t)1536 * 512;
    unsigned short* pwTh = (unsigned short*)qkv;
    unsigned short* pwTl = pwTh + (size_t)512 * 512;

    xsplit_kernel<<<M_ROWS * 512 / 2048, 256, 0, stream>>>(x, Xh, Xl);
    wsplit_kernel<<<3072, 256, 0, stream>>>(qkv_w, qwTh, qwTl, 1536);
    gemm_mfma_kernel<<<dim3(12, 1024), 256, 0, stream>>>(
        Xh, Xl, qwTh, qwTl, 0, qkv, nullptr, nullptr, 1536);
    attn_kernel<<<B_WIN * H_HEADS, 256, 0, stream>>>(
        qkv, bias_table, rel_index, attn_map, avh, avl);
    wsplit_kernel<<<1024, 256, 0, stream>>>(proj_w, pwTh, pwTl, 512);
    gemm_mfma_kernel<<<dim3(4, 1024), 256, 0, stream>>>(
        avh, avl, pwTh, pwTl, 1, nullptr, proj_b, out, 512);
}